// Round 5
// baseline (585.568 us; speedup 1.0000x reference)
//
#include <hip/hip_runtime.h>
#include <hip/hip_bf16.h>

// GPT-2 transformer block, MI355X bf16-MFMA. Round 12:
//  - attn_mfma restructured: QBLK=32 q-rows per wave (q-tile = 128 rows,
//    4 waves), k-tile = 64. K/V LDS frag reads are shared across the wave's
//    2 q-groups -> LDS ops per q*k fall x0.64 (attn was LDS-pipe-bound:
//    MfmaUtil 14 / VALU 52 / HBM 16, none saturated, ~270 LDS cyc vs 87
//    MFMA cyc per process). Paired q-tiles (qa, 15-qa) keep block work
//    uniform at 34 k-tile-works. 1-D grid 512, id=(g&7)+8*qa+64*(g>>3) so
//    all 8 blocks sharing one (b,h)'s K/V land on the SAME XCD (round-robin
//    dispatch) -> K/V cached once per L2 instead of 8x (FETCH 130->~80MB).
//  - gemm256 per-phase pipeline (T2+T3+T4+T5) unchanged from R11.
//  - split-K=2 for proj/ff2, partials fused into ln_kernel. Unchanged.

typedef __attribute__((ext_vector_type(8))) short bf16x8;  // MFMA A/B frag
typedef __attribute__((ext_vector_type(4))) float f32x4;   // MFMA C/D frag

__device__ __forceinline__ unsigned short f2b(float f) {  // RNE
  unsigned int u = __float_as_uint(f);
  u += 0x7fffu + ((u >> 16) & 1u);
  return (unsigned short)(u >> 16);
}
__device__ __forceinline__ unsigned int pk2b(float a, float b) {  // packed bf16x2
  __hip_bfloat162 h = __float22bfloat162_rn(make_float2(a, b));
  return *(unsigned int*)&h;
}
__device__ __forceinline__ void gload_lds16(const unsigned short* g, unsigned short* l) {
  __builtin_amdgcn_global_load_lds((const __attribute__((address_space(1))) void*)g,
                                   (__attribute__((address_space(3))) void*)l, 16, 0, 0);
}

// ---------------- fp32 -> bf16 elementwise ----------------
__global__ __launch_bounds__(256) void cvt_bf16(const float* __restrict__ in,
                                                unsigned short* __restrict__ out, long n) {
  long i = ((long)blockIdx.x * 256 + threadIdx.x) * 4;
  if (i >= n) return;
  float4 v = *(const float4*)(in + i);
  *(ushort4*)(out + i) = make_ushort4(f2b(v.x), f2b(v.y), f2b(v.z), f2b(v.w));
}

// ---------------- transpose fp32 [R,C] -> bf16 [C,R] ----------------
__global__ __launch_bounds__(256) void transpose_bf16(const float* __restrict__ in,
                                                      unsigned short* __restrict__ out,
                                                      int R, int C) {
  __shared__ float tile[32][33];
  int c0 = blockIdx.x * 32, r0 = blockIdx.y * 32;
  for (int i = threadIdx.y; i < 32; i += 8)
    tile[i][threadIdx.x] = in[(long)(r0 + i) * C + c0 + threadIdx.x];
  __syncthreads();
  for (int i = threadIdx.y; i < 32; i += 8)
    out[(long)(c0 + i) * R + r0 + threadIdx.x] = f2b(tile[threadIdx.x][i]);
}

// ---------------- 256^2 per-phase-pipelined bf16 MFMA GEMM ----------------
// A [M][Kstride] bf16, Bt [N][Kstride] bf16. K = chunk length, blockIdx.y =
// K-chunk (0 -> Cout +bias, 1 -> Cout2 raw partial). M fixed 8192.
// Requires K%32==0, K>=128, N%256==0, gridDim.x%8==0.
// EPI: 0=f32 out, 2=bf16+relu,
//      3=qkv split: gn<2048 -> qk[m][2048] (q cols scaled 0.125*log2e),
//                   gn>=2048 -> vt[b,h,s,t] packed ushort4 scatter.
template <int EPI>
__global__ __launch_bounds__(512, 2) void gemm256(const unsigned short* __restrict__ A,
                                                  const unsigned short* __restrict__ Bt,
                                                  const float* __restrict__ bias,
                                                  void* __restrict__ Cout,
                                                  void* __restrict__ Cout2,
                                                  int N, int K, int Kstride) {
  __shared__ __align__(16) unsigned short As[4][256 * 32];  // 64 KiB ring
  __shared__ __align__(16) unsigned short Bs[4][256 * 32];  // 64 KiB ring

  int tid = threadIdx.x;
  int wv = tid >> 6, lane = tid & 63, quad = lane >> 4, l16 = lane & 15;
  int wm = wv >> 2, wn = wv & 3;  // 2x4 wave grid; wave owns 128x64 of C

  // XCD-aware bijective swizzle (gridDim.x % 8 == 0), bm-fastest
  int nwg = gridDim.x, id = blockIdx.x;
  int sid = (id & 7) * (nwg >> 3) + (id >> 3);
  int bm256 = (sid & 31) * 256, bn256 = (sid >> 5) * 256;
  int chunk = blockIdx.y;
  long kbase = (long)chunk * K;

  // staging: tile = 256 rows x 32 cols; thread covers 16B chunks tid and
  // tid+512. LDS chunk (row, slot) holds global chunk d = slot ^ ((row>>1)&3).
  int row1 = tid >> 2, row2 = row1 + 128;
  long dsl = ((tid & 3) ^ ((tid >> 3) & 3)) * 8;  // inverse-swizzled source col
  const unsigned short* Ap1 = A + (long)(bm256 + row1) * Kstride + kbase + dsl;
  const unsigned short* Ap2 = A + (long)(bm256 + row2) * Kstride + kbase + dsl;
  const unsigned short* Bp1 = Bt + (long)(bn256 + row1) * Kstride + kbase + dsl;
  const unsigned short* Bp2 = Bt + (long)(bn256 + row2) * Kstride + kbase + dsl;
  int lo1 = wv * 512, lo2 = wv * 512 + 4096;

  f32x4 acc[8][4] = {};
  // read-side swizzled 16B slot: (quad ^ ((row>>1)&3))*8, row%16 == l16
  int sl8 = (quad ^ ((l16 >> 1) & 3)) * 8;
  int arow = wm * 128 + l16;  // + i*16
  int brow = wn * 64 + l16;   // + j*16

  int NT = K >> 5;  // always >= 16 here
  // prologue stages, issue order A0 B0 A1 B1 A2 (10 loads; newest 6 may fly)
  gload_lds16(Ap1, &As[0][lo1]); gload_lds16(Ap2, &As[0][lo2]);
  gload_lds16(Bp1, &Bs[0][lo1]); gload_lds16(Bp2, &Bs[0][lo2]);
  gload_lds16(Ap1 + 32, &As[1][lo1]); gload_lds16(Ap2 + 32, &As[1][lo2]);
  gload_lds16(Bp1 + 32, &Bs[1][lo1]); gload_lds16(Bp2 + 32, &Bs[1][lo2]);
  gload_lds16(Ap1 + 64, &As[2][lo1]); gload_lds16(Ap2 + 64, &As[2][lo2]);
  asm volatile("s_waitcnt vmcnt(6)\n\ts_barrier" ::: "memory");
  __builtin_amdgcn_sched_barrier(0);

  for (int tau = 0; tau < NT; ++tau) {
    const unsigned short* Ab = &As[tau & 3][0];
    const unsigned short* Bb = &Bs[tau & 3][0];
    bf16x8 af[4], bfr[4];
    // ---- even phase: read A i0-3 + B j0-3 (8 b128); stage B(tau+2); MFMA i0-3
#pragma unroll
    for (int i = 0; i < 4; ++i)
      af[i] = *(const bf16x8*)(Ab + (arow + i * 16) * 32 + sl8);
#pragma unroll
    for (int j = 0; j < 4; ++j)
      bfr[j] = *(const bf16x8*)(Bb + (brow + j * 16) * 32 + sl8);
    if (tau + 2 < NT) {
      long ko = (long)(tau + 2) * 32;
      int s = (tau + 2) & 3;
      gload_lds16(Bp1 + ko, &Bs[s][lo1]);
      gload_lds16(Bp2 + ko, &Bs[s][lo2]);
    }
    asm volatile("s_barrier\n\ts_waitcnt lgkmcnt(0)" ::: "memory");
    __builtin_amdgcn_sched_barrier(0);
    __builtin_amdgcn_s_setprio(1);
#pragma unroll
    for (int i = 0; i < 4; ++i)
#pragma unroll
      for (int j = 0; j < 4; ++j)
        acc[i][j] = __builtin_amdgcn_mfma_f32_16x16x32_bf16(af[i], bfr[j], acc[i][j], 0, 0, 0);
    __builtin_amdgcn_s_setprio(0);
    __builtin_amdgcn_s_barrier();
    __builtin_amdgcn_sched_barrier(0);
    // ---- odd phase: read A i4-7 (4 b128); stage A(tau+3); MFMA i4-7
    bf16x8 ag[4];
#pragma unroll
    for (int i = 0; i < 4; ++i)
      ag[i] = *(const bf16x8*)(Ab + (arow + (i + 4) * 16) * 32 + sl8);
    if (tau + 3 < NT) {
      long ko = (long)(tau + 3) * 32;
      int s = (tau + 3) & 3;
      gload_lds16(Ap1 + ko, &As[s][lo1]);
      gload_lds16(Ap2 + ko, &As[s][lo2]);
    }
    asm volatile("s_barrier\n\ts_waitcnt lgkmcnt(0)" ::: "memory");
    __builtin_amdgcn_sched_barrier(0);
    __builtin_amdgcn_s_setprio(1);
#pragma unroll
    for (int i = 0; i < 4; ++i)
#pragma unroll
      for (int j = 0; j < 4; ++j)
        acc[i + 4][j] = __builtin_amdgcn_mfma_f32_16x16x32_bf16(ag[i], bfr[j], acc[i + 4][j], 0, 0, 0);
    __builtin_amdgcn_s_setprio(0);
    // ---- once-per-tile counted gate + end barrier (tail: 6 -> 4 -> 0)
    if (tau + 3 < NT) {
      asm volatile("s_waitcnt vmcnt(6)\n\ts_barrier" ::: "memory");
    } else if (tau + 2 < NT) {
      asm volatile("s_waitcnt vmcnt(4)\n\ts_barrier" ::: "memory");
    } else if (tau + 1 < NT) {
      asm volatile("s_waitcnt vmcnt(0)\n\ts_barrier" ::: "memory");
    }
    __builtin_amdgcn_sched_barrier(0);
  }

  void* Cbase = chunk ? Cout2 : Cout;
#pragma unroll
  for (int i = 0; i < 8; ++i) {
#pragma unroll
    for (int j = 0; j < 4; ++j) {
      int gn = bn256 + wn * 64 + j * 16 + l16;
      float bv = chunk ? 0.f : bias[gn];
      if (EPI == 3 && gn >= 2048) {
        int h = (gn >> 6) & 15, s = gn & 63;
        int gm0 = bm256 + wm * 128 + i * 16 + quad * 4;
        int b = gm0 >> 11, tt0 = gm0 & 2047;
        unsigned short* vt = (unsigned short*)Cout + 16777216L;
        ushort4 us;
        us.x = f2b(acc[i][j][0] + bv);
        us.y = f2b(acc[i][j][1] + bv);
        us.z = f2b(acc[i][j][2] + bv);
        us.w = f2b(acc[i][j][3] + bv);
        *(ushort4*)(vt + (((long)(b * 16 + h)) * 64 + s) * 2048 + tt0) = us;
      } else {
#pragma unroll
        for (int r = 0; r < 4; ++r) {
          int gm = bm256 + wm * 128 + i * 16 + quad * 4 + r;
          float v = acc[i][j][r] + bv;
          if (EPI == 2) v = fmaxf(v, 0.f);
          if (EPI == 0) {
            ((float*)Cbase)[(long)gm * N + gn] = v;
          } else if (EPI == 2) {
            ((unsigned short*)Cbase)[(long)gm * N + gn] = f2b(v);
          } else {  // EPI==3, q/k rows
            float sc = (gn < 1024) ? 0.18033688011112042f : 1.0f;  // 0.125*log2(e)
            ((unsigned short*)Cbase)[(long)gm * 2048 + gn] = f2b(v * sc);
          }
        }
      }
    }
  }
}

// ---------------- MFMA flash attention (QBLK=32/wave, paired 128-row q-tiles) --
// qk[m][2048] (q cols 0..1023 pre-scaled by 0.125*log2e, k cols 1024..2047),
// vt[b,h,s,t] at elem offset 16M. 1-D grid 512, 256 thr = 4 waves.
// id = (g&7) + 8*qa + 64*(g>>3), g = h + 16*b: all 8 qa-blocks of one (b,h)
// share an XCD (K/V L2 locality). Block handles q-tiles qa and qb=15-qa
// (128 rows each): 2qb+2 staged k-tiles serve both -> 34 works, uniform.
// Wave w owns q rows [qt*128 + w*32, +32) as 2 q-groups of 16.
__global__ __launch_bounds__(256) void attn_mfma(const unsigned short* __restrict__ qkv,
                                                 unsigned short* __restrict__ outp) {
  const int LD = 72;  // 144 B row stride; b64/b128 accesses land 2-way (free)
  __shared__ __align__(16) unsigned short Ks[64 * LD];
  __shared__ __align__(16) unsigned short Vts[64 * LD];
  __shared__ __align__(16) unsigned short Ps[4][32 * LD];  // wave-private P rows
  int id = blockIdx.x;
  int qa = (id >> 3) & 7, qb = 15 - qa;
  int g = (id & 7) | ((id >> 6) << 3);
  int h = g & 15, b = g >> 4;
  int t = threadIdx.x;
  int w = t >> 6, lane = t & 63, quad = lane >> 4, l16 = lane & 15;
  const unsigned short* qg = qkv + (long)(b * 2048) * 2048 + h * 64;
  const unsigned short* kg = qg + 1024;
  const unsigned short* vg = qkv + 16777216L + (((long)(b * 16 + h)) * 64) * 2048;
  unsigned short* Pw = &Ps[w][0];

  // Q frags (B-operand for S^T): [qg][ks]; row = qt*128 + w*32 + qg*16 + l16
  bf16x8 qfa[2][2], qfb[2][2];
#pragma unroll
  for (int qq = 0; qq < 2; ++qq)
#pragma unroll
    for (int ks = 0; ks < 2; ++ks) {
      qfa[qq][ks] = *(const bf16x8*)(qg + (long)(qa * 128 + w * 32 + qq * 16 + l16) * 2048 + ks * 32 + quad * 8);
      qfb[qq][ks] = *(const bf16x8*)(qg + (long)(qb * 128 + w * 32 + qq * 16 + l16) * 2048 + ks * 32 + quad * 8);
    }

  int sr = t >> 2, sc = (t & 3) * 16;
  const unsigned short* kp = kg + (long)sr * 2048 + sc;
  const unsigned short* vp = vg + (long)sr * 2048 + sc;
  int4 kv0 = *(const int4*)kp, kv1 = *(const int4*)(kp + 8);
  int4 vv0 = *(const int4*)vp, vv1 = *(const int4*)(vp + 8);
  kp += (long)64 * 2048;
  vp += 64;

  f32x4 oa[2][4] = {}, ob[2][4] = {};
  f32x4 la[2] = {}, lb[2] = {};
  const short ONE = 0x3F80;
  bf16x8 ones = {ONE, ONE, ONE, ONE, ONE, ONE, ONE, ONE};

  // one k-tile (64 k) x 32 q rows: S^T -> exp2 -> P (LDS) -> PV + l
  auto process = [&](const bf16x8 (&qf)[2][2], int qt2, int kt,
                     f32x4 (&oacc)[2][4], f32x4 (&lacc)[2]) {
    int rel = kt - qt2;          // <=1 always for processed tiles
    bool diag = (rel >= 0);
    int off = rel << 6;          // k offset for causal mask
#pragma unroll
    for (int rg = 0; rg < 4; ++rg) {
      bf16x8 kf0 = *(const bf16x8*)(Ks + (rg * 16 + l16) * LD + quad * 8);
      bf16x8 kf1 = *(const bf16x8*)(Ks + (rg * 16 + l16) * LD + 32 + quad * 8);
#pragma unroll
      for (int qq = 0; qq < 2; ++qq) {
        f32x4 st = {};
        st = __builtin_amdgcn_mfma_f32_16x16x32_bf16(kf0, qf[qq][0], st, 0, 0, 0);
        st = __builtin_amdgcn_mfma_f32_16x16x32_bf16(kf1, qf[qq][1], st, 0, 0, 0);
        if (diag) {
          int kq = rg * 16 + quad * 4 + off;  // k row (+64 for 2nd diag tile)
          int qrow = w * 32 + qq * 16 + l16;  // q row within 128-tile
#pragma unroll
          for (int r = 0; r < 4; ++r)
            if (kq + r > qrow) st[r] = -1e30f;
        }
        unsigned int lo = pk2b(exp2f(st[0]), exp2f(st[1]));
        unsigned int hi = pk2b(exp2f(st[2]), exp2f(st[3]));
        *(uint2*)(Pw + (qq * 16 + l16) * LD + rg * 16 + quad * 4) = make_uint2(lo, hi);
      }
    }
#pragma unroll
    for (int kc = 0; kc < 2; ++kc) {
      bf16x8 ap0 = *(const bf16x8*)(Pw + l16 * LD + kc * 32 + quad * 8);
      bf16x8 ap1 = *(const bf16x8*)(Pw + (16 + l16) * LD + kc * 32 + quad * 8);
      lacc[0] = __builtin_amdgcn_mfma_f32_16x16x32_bf16(ap0, ones, lacc[0], 0, 0, 0);
      lacc[1] = __builtin_amdgcn_mfma_f32_16x16x32_bf16(ap1, ones, lacc[1], 0, 0, 0);
#pragma unroll
      for (int sg = 0; sg < 4; ++sg) {
        bf16x8 vf = *(const bf16x8*)(Vts + (sg * 16 + l16) * LD + kc * 32 + quad * 8);
        oacc[0][sg] = __builtin_amdgcn_mfma_f32_16x16x32_bf16(ap0, vf, oacc[0][sg], 0, 0, 0);
        oacc[1][sg] = __builtin_amdgcn_mfma_f32_16x16x32_bf16(ap1, vf, oacc[1][sg], 0, 0, 0);
      }
    }
  };

  int nkt = 2 * qb + 2;
  for (int kt = 0; kt < nkt; ++kt) {
    __syncthreads();
    *(int4*)(Ks + sr * LD + sc) = kv0;
    *(int4*)(Ks + sr * LD + sc + 8) = kv1;
    *(int4*)(Vts + sr * LD + sc) = vv0;
    *(int4*)(Vts + sr * LD + sc + 8) = vv1;
    __syncthreads();
    if (kt + 1 < nkt) {  // prefetch next tile behind compute
      kv0 = *(const int4*)kp; kv1 = *(const int4*)(kp + 8);
      vv0 = *(const int4*)vp; vv1 = *(const int4*)(vp + 8);
      kp += (long)64 * 2048;
      vp += 64;
    }
    process(qfb, 2 * qb, kt, ob, lb);           // heavy tile: every kt
    if (kt <= 2 * qa + 1) process(qfa, 2 * qa, kt, oa, la);  // light tile
  }

  auto epi = [&](int qt, f32x4 (&oacc)[2][4], f32x4 (&lacc)[2]) {
#pragma unroll
    for (int qq = 0; qq < 2; ++qq)
#pragma unroll
      for (int r = 0; r < 4; ++r) {
        float invl = 1.f / lacc[qq][r];
        int row = qt * 128 + w * 32 + qq * 16 + quad * 4 + r;
        unsigned short* op = outp + ((long)(b * 2048 + row)) * 1024 + h * 64;
#pragma unroll
        for (int sg = 0; sg < 4; ++sg) op[sg * 16 + l16] = f2b(oacc[qq][sg][r] * invl);
      }
  };
  epi(qa, oa, la);
  epi(qb, ob, lb);
}

// ---------------- residual + LayerNorm (optional 3rd addend: split-K partial) --
__global__ __launch_bounds__(256) void ln_kernel(const float* __restrict__ a,
                                                 const float* __restrict__ a2,
                                                 const float* __restrict__ res,
                                                 const float* __restrict__ gam,
                                                 const float* __restrict__ bet,
                                                 float* __restrict__ outf,
                                                 unsigned short* __restrict__ outb) {
  int row = blockIdx.x, t = threadIdx.x;
  float4 av = *(const float4*)(a + (long)row * 1024 + t * 4);
  float4 rv = *(const float4*)(res + (long)row * 1024 + t * 4);
  float v0 = av.x + rv.x, v1 = av.y + rv.y, v2 = av.z + rv.z, v3 = av.w + rv.w;
  if (a2) {
    float4 a2v = *(const float4*)(a2 + (long)row * 1024 + t * 4);
    v0 += a2v.x; v1 += a2v.y; v2 += a2v.z; v3 += a2v.w;
  }
  float s = v0 + v1 + v2 + v3;
  float ss = v0 * v0 + v1 * v1 + v2 * v2 + v3 * v3;
#pragma unroll
  for (int off = 32; off >= 1; off >>= 1) {
    s += __shfl_down(s, off);
    ss += __shfl_down(ss, off);
  }
  __shared__ float sb[4], ssb[4];
  __shared__ float mean_s, inv_s;
  int w = t >> 6, lane = t & 63;
  if (lane == 0) { sb[w] = s; ssb[w] = ss; }
  __syncthreads();
  if (t == 0) {
    float S = sb[0] + sb[1] + sb[2] + sb[3];
    float SS = ssb[0] + ssb[1] + ssb[2] + ssb[3];
    float mean = S * (1.f / 1024.f);
    float var = SS * (1.f / 1024.f) - mean * mean;
    mean_s = mean;
    inv_s = rsqrtf(var + 1e-5f);
  }
  __syncthreads();
  float mean = mean_s, inv = inv_s;
  int c = t * 4;
  float4 gv = *(const float4*)(gam + c);
  float4 bv = *(const float4*)(bet + c);
  float y0 = (v0 - mean) * inv * gv.x + bv.x;
  float y1 = (v1 - mean) * inv * gv.y + bv.y;
  float y2 = (v2 - mean) * inv * gv.z + bv.z;
  float y3 = (v3 - mean) * inv * gv.w + bv.w;
  *(float4*)(outf + (long)row * 1024 + c) = make_float4(y0, y1, y2, y3);
  if (outb) {
    *(ushort4*)(outb + (long)row * 1024 + c) = make_ushort4(f2b(y0), f2b(y1), f2b(y2), f2b(y3));
  }
}

extern "C" void kernel_launch(void* const* d_in, const int* in_sizes, int n_in,
                              void* d_out, int out_size, void* d_ws, size_t ws_size,
                              hipStream_t stream) {
  const float* x      = (const float*)d_in[0];
  const float* w_attn = (const float*)d_in[1];
  const float* b_attn = (const float*)d_in[2];
  const float* w_proj = (const float*)d_in[3];
  const float* b_proj = (const float*)d_in[4];
  const float* ln1_g  = (const float*)d_in[5];
  const float* ln1_b  = (const float*)d_in[6];
  const float* w_ff1  = (const float*)d_in[7];
  const float* b_ff1  = (const float*)d_in[8];
  const float* w_ff2  = (const float*)d_in[9];
  const float* b_ff2  = (const float*)d_in[10];
  const float* ln2_g  = (const float*)d_in[11];
  const float* ln2_b  = (const float*)d_in[12];

  const long M = 8192, E = 1024;
  char* ws = (char*)d_ws;
  unsigned short* xb   = (unsigned short*)ws; ws += M * E * 2;           // 16 MiB
  unsigned short* wTa  = (unsigned short*)ws; ws += 3072L * 1024 * 2;    // 6
  unsigned short* wTp  = (unsigned short*)ws; ws += 1024L * 1024 * 2;    // 2
  unsigned short* wTf1 = (unsigned short*)ws; ws += 4096L * 1024 * 2;    // 8
  unsigned short* wTf2 = (unsigned short*)ws; ws += 4096L * 1024 * 2;    // 8
  unsigned short* qkvb = (unsigned short*)ws; ws += M * 3072 * 2;        // 48 (qk rows 32 MiB | vt 16 MiB)
  unsigned short* attb = (unsigned short*)ws; ws += M * E * 2;           // 16
  float* a1f = (float*)ws; ws += M * E * 4;                              // 32
  float* x1f = (float*)ws; ws += M * E * 4;                              // 32
  unsigned short* x1b = (unsigned short*)ws; ws += M * E * 2;            // 16  => 184 MiB
  unsigned short* hb = qkvb;   // overlays consumed qkv+attb space
  float* f2 = a1f;
  // split-K partial buffers (reuse dead workspace, both 32 MiB fp32):
  float* prj1 = (float*)qkvb;   // qk region dead after attn; ln1 consumes before ff1
  float* ff21 = (float*)d_ws;   // xb+wTa+wTp+(part of)wTf1 dead by ff2

  cvt_bf16<<<dim3((M * E) / 4 / 256), dim3(256), 0, stream>>>(x, xb, M * E);
  transpose_bf16<<<dim3(3072 / 32, 1024 / 32), dim3(32, 8), 0, stream>>>(w_attn, wTa, 1024, 3072);
  transpose_bf16<<<dim3(1024 / 32, 1024 / 32), dim3(32, 8), 0, stream>>>(w_proj, wTp, 1024, 1024);
  transpose_bf16<<<dim3(4096 / 32, 1024 / 32), dim3(32, 8), 0, stream>>>(w_ff1, wTf1, 1024, 4096);
  transpose_bf16<<<dim3(1024 / 32, 4096 / 32), dim3(32, 8), 0, stream>>>(w_ff2, wTf2, 4096, 1024);
  // qkv projection (384 blocks), attention-layout epilogue
  gemm256<3><<<dim3(384, 1), dim3(512), 0, stream>>>(xb, wTa, b_attn, qkvb, nullptr, 3072, 1024, 1024);
  // MFMA flash attention (QBLK=32, XCD-grouped K/V)
  attn_mfma<<<dim3(512), dim3(256), 0, stream>>>(qkvb, attb);
  // attn output projection: split-K=2 -> 256 blocks = 1 full round
  gemm256<0><<<dim3(128, 2), dim3(512), 0, stream>>>(attb, wTp, b_proj, a1f, prj1, 1024, 512, 1024);
  ln_kernel<<<dim3(8192), dim3(256), 0, stream>>>(a1f, prj1, x, ln1_g, ln1_b, x1f, x1b);
  // ff1 (512 blocks = 2 rounds)
  gemm256<2><<<dim3(512, 1), dim3(512), 0, stream>>>(x1b, wTf1, b_ff1, hb, nullptr, 4096, 1024, 1024);
  // ff2: split-K=2 -> 256 blocks = 1 full round, K chunks of 2048
  gemm256<0><<<dim3(128, 2), dim3(512), 0, stream>>>(hb, wTf2, b_ff2, f2, ff21, 1024, 2048, 4096);
  ln_kernel<<<dim3(8192), dim3(256), 0, stream>>>(f2, ff21, x1f, ln2_g, ln2_b, (float*)d_out, nullptr);
}

// Round 6
// 571.672 us; speedup vs baseline: 1.0243x; 1.0243x over previous
//
#include <hip/hip_runtime.h>
#include <hip/hip_bf16.h>

// GPT-2 transformer block, MI355X bf16-MFMA. Round 13:
//  - attn_mfma: IN-REGISTER P. Swapped QK^T gives st(quad,l16) = P[q=l16][k].
//    Permuting the K-rows each S^T MFMA consumes (Ks row pi(aa,kc,m) =
//    8*(m>>2)+(m&3)+4*aa+32*kc) makes st(quad,r) hold exactly k = 8*quad +
//    (r+4aa) + 32kc -> pk2b packs the PV A-frag fully IN-LANE (q=l16 on both
//    sides). P's LDS round-trip (8 ds_write_b64 + 4 ds_read_b128 + 2 LDS
//    latencies per process) leaves the critical path; Ps buffer freed.
//    R5 evidence: time invariant under x0.67 LDS bytes + FETCH 130->25MB =>
//    chain-bound, so cut the chain.
//  - Ks/Vts: LD=64 + store-side XOR swizzle f(row)=(row&3)|((row>>3&1)<<2);
//    K-reads (fs = l16&7), V-reads, and staging writes all conflict-free.
//    Double-buffered (2x16KB) -> ONE barrier per k-tile (write buf^1 while
//    buf still being read; W(t+2) ordered behind bar(t+1)).
//  - QBLK=32/wave, paired 128-row q-tiles, XCD-grouped K/V grid: unchanged.
//  - gemm256 per-phase pipeline (T2+T3+T4+T5), split-K=2 + LN fusion:
//    unchanged from R11/R12.

typedef __attribute__((ext_vector_type(8))) short bf16x8;  // MFMA A/B frag
typedef __attribute__((ext_vector_type(4))) float f32x4;   // MFMA C/D frag

__device__ __forceinline__ unsigned short f2b(float f) {  // RNE
  unsigned int u = __float_as_uint(f);
  u += 0x7fffu + ((u >> 16) & 1u);
  return (unsigned short)(u >> 16);
}
__device__ __forceinline__ unsigned int pk2b(float a, float b) {  // packed bf16x2
  __hip_bfloat162 h = __float22bfloat162_rn(make_float2(a, b));
  return *(unsigned int*)&h;
}
__device__ __forceinline__ void gload_lds16(const unsigned short* g, unsigned short* l) {
  __builtin_amdgcn_global_load_lds((const __attribute__((address_space(1))) void*)g,
                                   (__attribute__((address_space(3))) void*)l, 16, 0, 0);
}

// ---------------- fp32 -> bf16 elementwise ----------------
__global__ __launch_bounds__(256) void cvt_bf16(const float* __restrict__ in,
                                                unsigned short* __restrict__ out, long n) {
  long i = ((long)blockIdx.x * 256 + threadIdx.x) * 4;
  if (i >= n) return;
  float4 v = *(const float4*)(in + i);
  *(ushort4*)(out + i) = make_ushort4(f2b(v.x), f2b(v.y), f2b(v.z), f2b(v.w));
}

// ---------------- transpose fp32 [R,C] -> bf16 [C,R] ----------------
__global__ __launch_bounds__(256) void transpose_bf16(const float* __restrict__ in,
                                                      unsigned short* __restrict__ out,
                                                      int R, int C) {
  __shared__ float tile[32][33];
  int c0 = blockIdx.x * 32, r0 = blockIdx.y * 32;
  for (int i = threadIdx.y; i < 32; i += 8)
    tile[i][threadIdx.x] = in[(long)(r0 + i) * C + c0 + threadIdx.x];
  __syncthreads();
  for (int i = threadIdx.y; i < 32; i += 8)
    out[(long)(c0 + i) * R + r0 + threadIdx.x] = f2b(tile[threadIdx.x][i]);
}

// ---------------- 256^2 per-phase-pipelined bf16 MFMA GEMM ----------------
// A [M][Kstride] bf16, Bt [N][Kstride] bf16. K = chunk length, blockIdx.y =
// K-chunk (0 -> Cout +bias, 1 -> Cout2 raw partial). M fixed 8192.
// Requires K%32==0, K>=128, N%256==0, gridDim.x%8==0.
// EPI: 0=f32 out, 2=bf16+relu,
//      3=qkv split: gn<2048 -> qk[m][2048] (q cols scaled 0.125*log2e),
//                   gn>=2048 -> vt[b,h,s,t] packed ushort4 scatter.
template <int EPI>
__global__ __launch_bounds__(512, 2) void gemm256(const unsigned short* __restrict__ A,
                                                  const unsigned short* __restrict__ Bt,
                                                  const float* __restrict__ bias,
                                                  void* __restrict__ Cout,
                                                  void* __restrict__ Cout2,
                                                  int N, int K, int Kstride) {
  __shared__ __align__(16) unsigned short As[4][256 * 32];  // 64 KiB ring
  __shared__ __align__(16) unsigned short Bs[4][256 * 32];  // 64 KiB ring

  int tid = threadIdx.x;
  int wv = tid >> 6, lane = tid & 63, quad = lane >> 4, l16 = lane & 15;
  int wm = wv >> 2, wn = wv & 3;  // 2x4 wave grid; wave owns 128x64 of C

  // XCD-aware bijective swizzle (gridDim.x % 8 == 0), bm-fastest
  int nwg = gridDim.x, id = blockIdx.x;
  int sid = (id & 7) * (nwg >> 3) + (id >> 3);
  int bm256 = (sid & 31) * 256, bn256 = (sid >> 5) * 256;
  int chunk = blockIdx.y;
  long kbase = (long)chunk * K;

  // staging: tile = 256 rows x 32 cols; thread covers 16B chunks tid and
  // tid+512. LDS chunk (row, slot) holds global chunk d = slot ^ ((row>>1)&3).
  int row1 = tid >> 2, row2 = row1 + 128;
  long dsl = ((tid & 3) ^ ((tid >> 3) & 3)) * 8;  // inverse-swizzled source col
  const unsigned short* Ap1 = A + (long)(bm256 + row1) * Kstride + kbase + dsl;
  const unsigned short* Ap2 = A + (long)(bm256 + row2) * Kstride + kbase + dsl;
  const unsigned short* Bp1 = Bt + (long)(bn256 + row1) * Kstride + kbase + dsl;
  const unsigned short* Bp2 = Bt + (long)(bn256 + row2) * Kstride + kbase + dsl;
  int lo1 = wv * 512, lo2 = wv * 512 + 4096;

  f32x4 acc[8][4] = {};
  // read-side swizzled 16B slot: (quad ^ ((row>>1)&3))*8, row%16 == l16
  int sl8 = (quad ^ ((l16 >> 1) & 3)) * 8;
  int arow = wm * 128 + l16;  // + i*16
  int brow = wn * 64 + l16;   // + j*16

  int NT = K >> 5;  // always >= 16 here
  // prologue stages, issue order A0 B0 A1 B1 A2 (10 loads; newest 6 may fly)
  gload_lds16(Ap1, &As[0][lo1]); gload_lds16(Ap2, &As[0][lo2]);
  gload_lds16(Bp1, &Bs[0][lo1]); gload_lds16(Bp2, &Bs[0][lo2]);
  gload_lds16(Ap1 + 32, &As[1][lo1]); gload_lds16(Ap2 + 32, &As[1][lo2]);
  gload_lds16(Bp1 + 32, &Bs[1][lo1]); gload_lds16(Bp2 + 32, &Bs[1][lo2]);
  gload_lds16(Ap1 + 64, &As[2][lo1]); gload_lds16(Ap2 + 64, &As[2][lo2]);
  asm volatile("s_waitcnt vmcnt(6)\n\ts_barrier" ::: "memory");
  __builtin_amdgcn_sched_barrier(0);

  for (int tau = 0; tau < NT; ++tau) {
    const unsigned short* Ab = &As[tau & 3][0];
    const unsigned short* Bb = &Bs[tau & 3][0];
    bf16x8 af[4], bfr[4];
    // ---- even phase: read A i0-3 + B j0-3 (8 b128); stage B(tau+2); MFMA i0-3
#pragma unroll
    for (int i = 0; i < 4; ++i)
      af[i] = *(const bf16x8*)(Ab + (arow + i * 16) * 32 + sl8);
#pragma unroll
    for (int j = 0; j < 4; ++j)
      bfr[j] = *(const bf16x8*)(Bb + (brow + j * 16) * 32 + sl8);
    if (tau + 2 < NT) {
      long ko = (long)(tau + 2) * 32;
      int s = (tau + 2) & 3;
      gload_lds16(Bp1 + ko, &Bs[s][lo1]);
      gload_lds16(Bp2 + ko, &Bs[s][lo2]);
    }
    asm volatile("s_barrier\n\ts_waitcnt lgkmcnt(0)" ::: "memory");
    __builtin_amdgcn_sched_barrier(0);
    __builtin_amdgcn_s_setprio(1);
#pragma unroll
    for (int i = 0; i < 4; ++i)
#pragma unroll
      for (int j = 0; j < 4; ++j)
        acc[i][j] = __builtin_amdgcn_mfma_f32_16x16x32_bf16(af[i], bfr[j], acc[i][j], 0, 0, 0);
    __builtin_amdgcn_s_setprio(0);
    __builtin_amdgcn_s_barrier();
    __builtin_amdgcn_sched_barrier(0);
    // ---- odd phase: read A i4-7 (4 b128); stage A(tau+3); MFMA i4-7
    bf16x8 ag[4];
#pragma unroll
    for (int i = 0; i < 4; ++i)
      ag[i] = *(const bf16x8*)(Ab + (arow + (i + 4) * 16) * 32 + sl8);
    if (tau + 3 < NT) {
      long ko = (long)(tau + 3) * 32;
      int s = (tau + 3) & 3;
      gload_lds16(Ap1 + ko, &As[s][lo1]);
      gload_lds16(Ap2 + ko, &As[s][lo2]);
    }
    asm volatile("s_barrier\n\ts_waitcnt lgkmcnt(0)" ::: "memory");
    __builtin_amdgcn_sched_barrier(0);
    __builtin_amdgcn_s_setprio(1);
#pragma unroll
    for (int i = 0; i < 4; ++i)
#pragma unroll
      for (int j = 0; j < 4; ++j)
        acc[i + 4][j] = __builtin_amdgcn_mfma_f32_16x16x32_bf16(ag[i], bfr[j], acc[i + 4][j], 0, 0, 0);
    __builtin_amdgcn_s_setprio(0);
    // ---- once-per-tile counted gate + end barrier (tail: 6 -> 4 -> 0)
    if (tau + 3 < NT) {
      asm volatile("s_waitcnt vmcnt(6)\n\ts_barrier" ::: "memory");
    } else if (tau + 2 < NT) {
      asm volatile("s_waitcnt vmcnt(4)\n\ts_barrier" ::: "memory");
    } else if (tau + 1 < NT) {
      asm volatile("s_waitcnt vmcnt(0)\n\ts_barrier" ::: "memory");
    }
    __builtin_amdgcn_sched_barrier(0);
  }

  void* Cbase = chunk ? Cout2 : Cout;
#pragma unroll
  for (int i = 0; i < 8; ++i) {
#pragma unroll
    for (int j = 0; j < 4; ++j) {
      int gn = bn256 + wn * 64 + j * 16 + l16;
      float bv = chunk ? 0.f : bias[gn];
      if (EPI == 3 && gn >= 2048) {
        int h = (gn >> 6) & 15, s = gn & 63;
        int gm0 = bm256 + wm * 128 + i * 16 + quad * 4;
        int b = gm0 >> 11, tt0 = gm0 & 2047;
        unsigned short* vt = (unsigned short*)Cout + 16777216L;
        ushort4 us;
        us.x = f2b(acc[i][j][0] + bv);
        us.y = f2b(acc[i][j][1] + bv);
        us.z = f2b(acc[i][j][2] + bv);
        us.w = f2b(acc[i][j][3] + bv);
        *(ushort4*)(vt + (((long)(b * 16 + h)) * 64 + s) * 2048 + tt0) = us;
      } else {
#pragma unroll
        for (int r = 0; r < 4; ++r) {
          int gm = bm256 + wm * 128 + i * 16 + quad * 4 + r;
          float v = acc[i][j][r] + bv;
          if (EPI == 2) v = fmaxf(v, 0.f);
          if (EPI == 0) {
            ((float*)Cbase)[(long)gm * N + gn] = v;
          } else if (EPI == 2) {
            ((unsigned short*)Cbase)[(long)gm * N + gn] = f2b(v);
          } else {  // EPI==3, q/k rows
            float sc = (gn < 1024) ? 0.18033688011112042f : 1.0f;  // 0.125*log2(e)
            ((unsigned short*)Cbase)[(long)gm * 2048 + gn] = f2b(v * sc);
          }
        }
      }
    }
  }
}

// ---------------- MFMA flash attention (in-register P, one barrier/tile) ------
// qk[m][2048] (q cols 0..1023 pre-scaled by 0.125*log2e, k cols 1024..2047),
// vt[b,h,s,t] at elem offset 16M. 1-D grid 512, 256 thr = 4 waves.
// id = (g&7) + 8*qa + 64*(g>>3), g = h + 16*b (8 qa-blocks of a (b,h) share
// an XCD). Block: q-tiles qa and qb=15-qa (128 rows). Wave w: 32 q rows.
// K-row permutation pi(aa,kc,m) = 8*(m>>2)+(m&3)+4*aa+32*kc makes st(quad,r)
// hold k = 8*quad+(r+4aa)+32kc -> PV A-frag packs fully in-lane (q=l16).
// Ks/Vts: LD=64, XOR swizzle f(row)=(row&3)|((row>>3&1)<<2) on 16B slots;
// double-buffered, ONE barrier per k-tile.
__global__ __launch_bounds__(256) void attn_mfma(const unsigned short* __restrict__ qkv,
                                                 unsigned short* __restrict__ outp) {
  __shared__ __align__(16) unsigned short Ks[2][64 * 64];
  __shared__ __align__(16) unsigned short Vts[2][64 * 64];
  int id = blockIdx.x;
  int qa = (id >> 3) & 7, qb = 15 - qa;
  int g = (id & 7) | ((id >> 6) << 3);
  int h = g & 15, b = g >> 4;
  int t = threadIdx.x;
  int w = t >> 6, lane = t & 63, quad = lane >> 4, l16 = lane & 15;
  const unsigned short* qg = qkv + (long)(b * 2048) * 2048 + h * 64;
  const unsigned short* kg = qg + 1024;
  const unsigned short* vg = qkv + 16777216L + (((long)(b * 16 + h)) * 64) * 2048;

  // Q frags (B-operand for S^T): [qg][ks]; row = qt*128 + w*32 + qg*16 + l16
  bf16x8 qfa[2][2], qfb[2][2];
#pragma unroll
  for (int qq = 0; qq < 2; ++qq)
#pragma unroll
    for (int ks = 0; ks < 2; ++ks) {
      qfa[qq][ks] = *(const bf16x8*)(qg + (long)(qa * 128 + w * 32 + qq * 16 + l16) * 2048 + ks * 32 + quad * 8);
      qfb[qq][ks] = *(const bf16x8*)(qg + (long)(qb * 128 + w * 32 + qq * 16 + l16) * 2048 + ks * 32 + quad * 8);
    }

  int sr = t >> 2, c4 = t & 3;
  int fsr = (sr & 3) | (((sr >> 3) & 1) << 2);          // store-side swizzle
  int ws0 = sr * 64 + (((2 * c4) ^ fsr) * 8);           // slot 2c
  int ws1 = sr * 64 + (((2 * c4 + 1) ^ fsr) * 8);       // slot 2c+1
  const unsigned short* kp = kg + (long)sr * 2048 + c4 * 16;
  const unsigned short* vp = vg + (long)sr * 2048 + c4 * 16;
  int4 kv0 = *(const int4*)kp, kv1 = *(const int4*)(kp + 8);
  int4 vv0 = *(const int4*)vp, vv1 = *(const int4*)(vp + 8);
  kp += (long)64 * 2048;
  vp += 64;

  f32x4 oa[2][4] = {}, ob[2][4] = {};
  f32x4 la[2] = {}, lb[2] = {};
  const short ONE = 0x3F80;
  bf16x8 ones = {ONE, ONE, ONE, ONE, ONE, ONE, ONE, ONE};

  int fs = l16 & 7;                                     // f(pi-row) for K reads
  int fv = (l16 & 3) | (((l16 >> 3) & 1) << 2);         // f(row) for V reads

  // one k-tile (64 k) x 32 q rows, P fully in-register
  auto process = [&](const bf16x8 (&qf)[2][2], int qt2, int kt,
                     f32x4 (&oacc)[2][4], f32x4 (&lacc)[2],
                     const unsigned short* Kb, const unsigned short* Vb) {
    int rel = kt - qt2;
    bool diag = (rel >= 0);
    int off = rel << 6;
#pragma unroll
    for (int kc = 0; kc < 2; ++kc) {
      unsigned int apw[2][4];
#pragma unroll
      for (int aa = 0; aa < 2; ++aa) {
        int row = 8 * (l16 >> 2) + (l16 & 3) + 4 * aa + 32 * kc;  // pi(aa,kc,l16)
        const unsigned short* kr = Kb + row * 64;
        bf16x8 kf0 = *(const bf16x8*)(kr + (quad ^ fs) * 8);
        bf16x8 kf1 = *(const bf16x8*)(kr + ((quad ^ 4 ^ fs)) * 8);
#pragma unroll
        for (int qq = 0; qq < 2; ++qq) {
          f32x4 st = {};
          st = __builtin_amdgcn_mfma_f32_16x16x32_bf16(kf0, qf[qq][0], st, 0, 0, 0);
          st = __builtin_amdgcn_mfma_f32_16x16x32_bf16(kf1, qf[qq][1], st, 0, 0, 0);
          if (diag) {
            int kq = 8 * quad + 4 * aa + 32 * kc + off;
            int qrow = w * 32 + qq * 16 + l16;
#pragma unroll
            for (int r = 0; r < 4; ++r)
              if (kq + r > qrow) st[r] = -1e30f;
          }
          apw[qq][aa * 2]     = pk2b(exp2f(st[0]), exp2f(st[1]));
          apw[qq][aa * 2 + 1] = pk2b(exp2f(st[2]), exp2f(st[3]));
        }
      }
      union { unsigned int u[4]; bf16x8 v; } ap0, ap1;
#pragma unroll
      for (int u = 0; u < 4; ++u) { ap0.u[u] = apw[0][u]; ap1.u[u] = apw[1][u]; }
      lacc[0] = __builtin_amdgcn_mfma_f32_16x16x32_bf16(ap0.v, ones, lacc[0], 0, 0, 0);
      lacc[1] = __builtin_amdgcn_mfma_f32_16x16x32_bf16(ap1.v, ones, lacc[1], 0, 0, 0);
#pragma unroll
      for (int sg = 0; sg < 4; ++sg) {
        int vrow = sg * 16 + l16;
        bf16x8 vf = *(const bf16x8*)(Vb + vrow * 64 + (((4 * kc + quad) ^ fv) * 8));
        oacc[0][sg] = __builtin_amdgcn_mfma_f32_16x16x32_bf16(ap0.v, vf, oacc[0][sg], 0, 0, 0);
        oacc[1][sg] = __builtin_amdgcn_mfma_f32_16x16x32_bf16(ap1.v, vf, oacc[1][sg], 0, 0, 0);
      }
    }
  };

  int nkt = 2 * qb + 2;
  for (int kt = 0; kt < nkt; ++kt) {
    unsigned short* Kb = &Ks[kt & 1][0];
    unsigned short* Vb = &Vts[kt & 1][0];
    // stage this tile (regs loaded last iter; vmcnt enforced by reg deps)
    *(int4*)(Kb + ws0) = kv0;
    *(int4*)(Kb + ws1) = kv1;
    *(int4*)(Vb + ws0) = vv0;
    *(int4*)(Vb + ws1) = vv1;
    __syncthreads();
    if (kt + 1 < nkt) {  // prefetch next tile behind compute
      kv0 = *(const int4*)kp; kv1 = *(const int4*)(kp + 8);
      vv0 = *(const int4*)vp; vv1 = *(const int4*)(vp + 8);
      kp += (long)64 * 2048;
      vp += 64;
    }
    process(qfb, 2 * qb, kt, ob, lb, Kb, Vb);                    // heavy tile
    if (kt <= 2 * qa + 1) process(qfa, 2 * qa, kt, oa, la, Kb, Vb);  // light
  }

  auto epi = [&](int qt, f32x4 (&oacc)[2][4], f32x4 (&lacc)[2]) {
#pragma unroll
    for (int qq = 0; qq < 2; ++qq)
#pragma unroll
      for (int r = 0; r < 4; ++r) {
        float invl = 1.f / lacc[qq][r];
        int row = qt * 128 + w * 32 + qq * 16 + quad * 4 + r;
        unsigned short* op = outp + ((long)(b * 2048 + row)) * 1024 + h * 64;
#pragma unroll
        for (int sg = 0; sg < 4; ++sg) op[sg * 16 + l16] = f2b(oacc[qq][sg][r] * invl);
      }
  };
  epi(qa, oa, la);
  epi(qb, ob, lb);
}

// ---------------- residual + LayerNorm (optional 3rd addend: split-K partial) --
__global__ __launch_bounds__(256) void ln_kernel(const float* __restrict__ a,
                                                 const float* __restrict__ a2,
                                                 const float* __restrict__ res,
                                                 const float* __restrict__ gam,
                                                 const float* __restrict__ bet,
                                                 float* __restrict__ outf,
                                                 unsigned short* __restrict__ outb) {
  int row = blockIdx.x, t = threadIdx.x;
  float4 av = *(const float4*)(a + (long)row * 1024 + t * 4);
  float4 rv = *(const float4*)(res + (long)row * 1024 + t * 4);
  float v0 = av.x + rv.x, v1 = av.y + rv.y, v2 = av.z + rv.z, v3 = av.w + rv.w;
  if (a2) {
    float4 a2v = *(const float4*)(a2 + (long)row * 1024 + t * 4);
    v0 += a2v.x; v1 += a2v.y; v2 += a2v.z; v3 += a2v.w;
  }
  float s = v0 + v1 + v2 + v3;
  float ss = v0 * v0 + v1 * v1 + v2 * v2 + v3 * v3;
#pragma unroll
  for (int off = 32; off >= 1; off >>= 1) {
    s += __shfl_down(s, off);
    ss += __shfl_down(ss, off);
  }
  __shared__ float sb[4], ssb[4];
  __shared__ float mean_s, inv_s;
  int w = t >> 6, lane = t & 63;
  if (lane == 0) { sb[w] = s; ssb[w] = ss; }
  __syncthreads();
  if (t == 0) {
    float S = sb[0] + sb[1] + sb[2] + sb[3];
    float SS = ssb[0] + ssb[1] + ssb[2] + ssb[3];
    float mean = S * (1.f / 1024.f);
    float var = SS * (1.f / 1024.f) - mean * mean;
    mean_s = mean;
    inv_s = rsqrtf(var + 1e-5f);
  }
  __syncthreads();
  float mean = mean_s, inv = inv_s;
  int c = t * 4;
  float4 gv = *(const float4*)(gam + c);
  float4 bv = *(const float4*)(bet + c);
  float y0 = (v0 - mean) * inv * gv.x + bv.x;
  float y1 = (v1 - mean) * inv * gv.y + bv.y;
  float y2 = (v2 - mean) * inv * gv.z + bv.z;
  float y3 = (v3 - mean) * inv * gv.w + bv.w;
  *(float4*)(outf + (long)row * 1024 + c) = make_float4(y0, y1, y2, y3);
  if (outb) {
    *(ushort4*)(outb + (long)row * 1024 + c) = make_ushort4(f2b(y0), f2b(y1), f2b(y2), f2b(y3));
  }
}

extern "C" void kernel_launch(void* const* d_in, const int* in_sizes, int n_in,
                              void* d_out, int out_size, void* d_ws, size_t ws_size,
                              hipStream_t stream) {
  const float* x      = (const float*)d_in[0];
  const float* w_attn = (const float*)d_in[1];
  const float* b_attn = (const float*)d_in[2];
  const float* w_proj = (const float*)d_in[3];
  const float* b_proj = (const float*)d_in[4];
  const float* ln1_g  = (const float*)d_in[5];
  const float* ln1_b  = (const float*)d_in[6];
  const float* w_ff1  = (const float*)d_in[7];
  const float* b_ff1  = (const float*)d_in[8];
  const float* w_ff2  = (const float*)d_in[9];
  const float* b_ff2  = (const float*)d_in[10];
  const float* ln2_g  = (const float*)d_in[11];
  const float* ln2_b  = (const float*)d_in[12];

  const long M = 8192, E = 1024;
  char* ws = (char*)d_ws;
  unsigned short* xb   = (unsigned short*)ws; ws += M * E * 2;           // 16 MiB
  unsigned short* wTa  = (unsigned short*)ws; ws += 3072L * 1024 * 2;    // 6
  unsigned short* wTp  = (unsigned short*)ws; ws += 1024L * 1024 * 2;    // 2
  unsigned short* wTf1 = (unsigned short*)ws; ws += 4096L * 1024 * 2;    // 8
  unsigned short* wTf2 = (unsigned short*)ws; ws += 4096L * 1024 * 2;    // 8
  unsigned short* qkvb = (unsigned short*)ws; ws += M * 3072 * 2;        // 48 (qk rows 32 MiB | vt 16 MiB)
  unsigned short* attb = (unsigned short*)ws; ws += M * E * 2;           // 16
  float* a1f = (float*)ws; ws += M * E * 4;                              // 32
  float* x1f = (float*)ws; ws += M * E * 4;                              // 32
  unsigned short* x1b = (unsigned short*)ws; ws += M * E * 2;            // 16  => 184 MiB
  unsigned short* hb = qkvb;   // overlays consumed qkv+attb space
  float* f2 = a1f;
  // split-K partial buffers (reuse dead workspace, both 32 MiB fp32):
  float* prj1 = (float*)qkvb;   // qk region dead after attn; ln1 consumes before ff1
  float* ff21 = (float*)d_ws;   // xb+wTa+wTp+(part of)wTf1 dead by ff2

  cvt_bf16<<<dim3((M * E) / 4 / 256), dim3(256), 0, stream>>>(x, xb, M * E);
  transpose_bf16<<<dim3(3072 / 32, 1024 / 32), dim3(32, 8), 0, stream>>>(w_attn, wTa, 1024, 3072);
  transpose_bf16<<<dim3(1024 / 32, 1024 / 32), dim3(32, 8), 0, stream>>>(w_proj, wTp, 1024, 1024);
  transpose_bf16<<<dim3(4096 / 32, 1024 / 32), dim3(32, 8), 0, stream>>>(w_ff1, wTf1, 1024, 4096);
  transpose_bf16<<<dim3(1024 / 32, 4096 / 32), dim3(32, 8), 0, stream>>>(w_ff2, wTf2, 4096, 1024);
  // qkv projection (384 blocks), attention-layout epilogue
  gemm256<3><<<dim3(384, 1), dim3(512), 0, stream>>>(xb, wTa, b_attn, qkvb, nullptr, 3072, 1024, 1024);
  // MFMA flash attention (in-register P, XCD-grouped K/V)
  attn_mfma<<<dim3(512), dim3(256), 0, stream>>>(qkvb, attb);
  // attn output projection: split-K=2 -> 256 blocks = 1 full round
  gemm256<0><<<dim3(128, 2), dim3(512), 0, stream>>>(attb, wTp, b_proj, a1f, prj1, 1024, 512, 1024);
  ln_kernel<<<dim3(8192), dim3(256), 0, stream>>>(a1f, prj1, x, ln1_g, ln1_b, x1f, x1b);
  // ff1 (512 blocks = 2 rounds)
  gemm256<2><<<dim3(512, 1), dim3(512), 0, stream>>>(x1b, wTf1, b_ff1, hb, nullptr, 4096, 1024, 1024);
  // ff2: split-K=2 -> 256 blocks = 1 full round, K chunks of 2048
  gemm256<0><<<dim3(128, 2), dim3(512), 0, stream>>>(hb, wTf2, b_ff2, f2, ff21, 1024, 2048, 4096);
  ln_kernel<<<dim3(8192), dim3(256), 0, stream>>>(f2, ff21, x1f, ln2_g, ln2_b, (float*)d_out, nullptr);
}

// Round 9
// 542.131 us; speedup vs baseline: 1.0801x; 1.0545x over previous
//
#include <hip/hip_runtime.h>
#include <hip/hip_bf16.h>

// GPT-2 transformer block, MI355X bf16-MFMA. Round 16 (= R14/R15 with the
// __launch_bounds__(256,4) VGPR cap removed — the only codegen-level delta
// vs the passing R13; R14/R15 both died in-container with no counters):
//  - attn_mfma: in-register-P chain + doubled block concurrency.
//    R12/R13 both ~116us with VALU ~50 / Mfma ~15 / HBM <5 regardless of
//    LDS traffic, L2 locality, or chain length => latency-chain-bound at
//    2 waves/SIMD. Fix: 64-row paired q-tiles (qa, 31-qa), qa in [0,16)
//    -> 1024 uniform blocks (33 works each), ~3 blocks/CU at natural VGPR.
//  - in-register P: swapped QK^T + K-row permutation pi(aa,kc,m) =
//    8*(m>>2)+(m&3)+4*aa+32*kc makes st(quad,r) hold k=8quad+(r+4aa)+32kc;
//    pk2b packs PV A-frags in-lane; P never touches LDS.
//  - Ks/Vts: LD=64, store-side XOR swizzle f(row)=(row&3)|((row>>3&1)<<2),
//    double-buffered, one barrier per k-tile. Conflict-free (R13: 0 confl).
//  - XCD grouping: id=(g&7)+8*qa+128*(g>>3) -> all pair-blocks of a (b,h)
//    on one XCD (FETCH 130->25MB).
//  - gemm256 per-phase pipeline (T2+T3+T4+T5), split-K=2 + LN fusion:
//    unchanged from R11.

typedef __attribute__((ext_vector_type(8))) short bf16x8;  // MFMA A/B frag
typedef __attribute__((ext_vector_type(4))) float f32x4;   // MFMA C/D frag

__device__ __forceinline__ unsigned short f2b(float f) {  // RNE
  unsigned int u = __float_as_uint(f);
  u += 0x7fffu + ((u >> 16) & 1u);
  return (unsigned short)(u >> 16);
}
__device__ __forceinline__ unsigned int pk2b(float a, float b) {  // packed bf16x2
  __hip_bfloat162 h = __float22bfloat162_rn(make_float2(a, b));
  return *(unsigned int*)&h;
}
__device__ __forceinline__ void gload_lds16(const unsigned short* g, unsigned short* l) {
  __builtin_amdgcn_global_load_lds((const __attribute__((address_space(1))) void*)g,
                                   (__attribute__((address_space(3))) void*)l, 16, 0, 0);
}

// ---------------- fp32 -> bf16 elementwise ----------------
__global__ __launch_bounds__(256) void cvt_bf16(const float* __restrict__ in,
                                                unsigned short* __restrict__ out, long n) {
  long i = ((long)blockIdx.x * 256 + threadIdx.x) * 4;
  if (i >= n) return;
  float4 v = *(const float4*)(in + i);
  *(ushort4*)(out + i) = make_ushort4(f2b(v.x), f2b(v.y), f2b(v.z), f2b(v.w));
}

// ---------------- transpose fp32 [R,C] -> bf16 [C,R] ----------------
__global__ __launch_bounds__(256) void transpose_bf16(const float* __restrict__ in,
                                                      unsigned short* __restrict__ out,
                                                      int R, int C) {
  __shared__ float tile[32][33];
  int c0 = blockIdx.x * 32, r0 = blockIdx.y * 32;
  for (int i = threadIdx.y; i < 32; i += 8)
    tile[i][threadIdx.x] = in[(long)(r0 + i) * C + c0 + threadIdx.x];
  __syncthreads();
  for (int i = threadIdx.y; i < 32; i += 8)
    out[(long)(c0 + i) * R + r0 + threadIdx.x] = f2b(tile[threadIdx.x][i]);
}

// ---------------- 256^2 per-phase-pipelined bf16 MFMA GEMM ----------------
// A [M][Kstride] bf16, Bt [N][Kstride] bf16. K = chunk length, blockIdx.y =
// K-chunk (0 -> Cout +bias, 1 -> Cout2 raw partial). M fixed 8192.
// Requires K%32==0, K>=128, N%256==0, gridDim.x%8==0.
// EPI: 0=f32 out, 2=bf16+relu,
//      3=qkv split: gn<2048 -> qk[m][2048] (q cols scaled 0.125*log2e),
//                   gn>=2048 -> vt[b,h,s,t] packed ushort4 scatter.
template <int EPI>
__global__ __launch_bounds__(512, 2) void gemm256(const unsigned short* __restrict__ A,
                                                  const unsigned short* __restrict__ Bt,
                                                  const float* __restrict__ bias,
                                                  void* __restrict__ Cout,
                                                  void* __restrict__ Cout2,
                                                  int N, int K, int Kstride) {
  __shared__ __align__(16) unsigned short As[4][256 * 32];  // 64 KiB ring
  __shared__ __align__(16) unsigned short Bs[4][256 * 32];  // 64 KiB ring

  int tid = threadIdx.x;
  int wv = tid >> 6, lane = tid & 63, quad = lane >> 4, l16 = lane & 15;
  int wm = wv >> 2, wn = wv & 3;  // 2x4 wave grid; wave owns 128x64 of C

  // XCD-aware bijective swizzle (gridDim.x % 8 == 0), bm-fastest
  int nwg = gridDim.x, id = blockIdx.x;
  int sid = (id & 7) * (nwg >> 3) + (id >> 3);
  int bm256 = (sid & 31) * 256, bn256 = (sid >> 5) * 256;
  int chunk = blockIdx.y;
  long kbase = (long)chunk * K;

  // staging: tile = 256 rows x 32 cols; thread covers 16B chunks tid and
  // tid+512. LDS chunk (row, slot) holds global chunk d = slot ^ ((row>>1)&3).
  int row1 = tid >> 2, row2 = row1 + 128;
  long dsl = ((tid & 3) ^ ((tid >> 3) & 3)) * 8;  // inverse-swizzled source col
  const unsigned short* Ap1 = A + (long)(bm256 + row1) * Kstride + kbase + dsl;
  const unsigned short* Ap2 = A + (long)(bm256 + row2) * Kstride + kbase + dsl;
  const unsigned short* Bp1 = Bt + (long)(bn256 + row1) * Kstride + kbase + dsl;
  const unsigned short* Bp2 = Bt + (long)(bn256 + row2) * Kstride + kbase + dsl;
  int lo1 = wv * 512, lo2 = wv * 512 + 4096;

  f32x4 acc[8][4] = {};
  // read-side swizzled 16B slot: (quad ^ ((row>>1)&3))*8, row%16 == l16
  int sl8 = (quad ^ ((l16 >> 1) & 3)) * 8;
  int arow = wm * 128 + l16;  // + i*16
  int brow = wn * 64 + l16;   // + j*16

  int NT = K >> 5;  // always >= 16 here
  // prologue stages, issue order A0 B0 A1 B1 A2 (10 loads; newest 6 may fly)
  gload_lds16(Ap1, &As[0][lo1]); gload_lds16(Ap2, &As[0][lo2]);
  gload_lds16(Bp1, &Bs[0][lo1]); gload_lds16(Bp2, &Bs[0][lo2]);
  gload_lds16(Ap1 + 32, &As[1][lo1]); gload_lds16(Ap2 + 32, &As[1][lo2]);
  gload_lds16(Bp1 + 32, &Bs[1][lo1]); gload_lds16(Bp2 + 32, &Bs[1][lo2]);
  gload_lds16(Ap1 + 64, &As[2][lo1]); gload_lds16(Ap2 + 64, &As[2][lo2]);
  asm volatile("s_waitcnt vmcnt(6)\n\ts_barrier" ::: "memory");
  __builtin_amdgcn_sched_barrier(0);

  for (int tau = 0; tau < NT; ++tau) {
    const unsigned short* Ab = &As[tau & 3][0];
    const unsigned short* Bb = &Bs[tau & 3][0];
    bf16x8 af[4], bfr[4];
    // ---- even phase: read A i0-3 + B j0-3 (8 b128); stage B(tau+2); MFMA i0-3
#pragma unroll
    for (int i = 0; i < 4; ++i)
      af[i] = *(const bf16x8*)(Ab + (arow + i * 16) * 32 + sl8);
#pragma unroll
    for (int j = 0; j < 4; ++j)
      bfr[j] = *(const bf16x8*)(Bb + (brow + j * 16) * 32 + sl8);
    if (tau + 2 < NT) {
      long ko = (long)(tau + 2) * 32;
      int s = (tau + 2) & 3;
      gload_lds16(Bp1 + ko, &Bs[s][lo1]);
      gload_lds16(Bp2 + ko, &Bs[s][lo2]);
    }
    asm volatile("s_barrier\n\ts_waitcnt lgkmcnt(0)" ::: "memory");
    __builtin_amdgcn_sched_barrier(0);
    __builtin_amdgcn_s_setprio(1);
#pragma unroll
    for (int i = 0; i < 4; ++i)
#pragma unroll
      for (int j = 0; j < 4; ++j)
        acc[i][j] = __builtin_amdgcn_mfma_f32_16x16x32_bf16(af[i], bfr[j], acc[i][j], 0, 0, 0);
    __builtin_amdgcn_s_setprio(0);
    __builtin_amdgcn_s_barrier();
    __builtin_amdgcn_sched_barrier(0);
    // ---- odd phase: read A i4-7 (4 b128); stage A(tau+3); MFMA i4-7
    bf16x8 ag[4];
#pragma unroll
    for (int i = 0; i < 4; ++i)
      ag[i] = *(const bf16x8*)(Ab + (arow + (i + 4) * 16) * 32 + sl8);
    if (tau + 3 < NT) {
      long ko = (long)(tau + 3) * 32;
      int s = (tau + 3) & 3;
      gload_lds16(Ap1 + ko, &As[s][lo1]);
      gload_lds16(Ap2 + ko, &As[s][lo2]);
    }
    asm volatile("s_barrier\n\ts_waitcnt lgkmcnt(0)" ::: "memory");
    __builtin_amdgcn_sched_barrier(0);
    __builtin_amdgcn_s_setprio(1);
#pragma unroll
    for (int i = 0; i < 4; ++i)
#pragma unroll
      for (int j = 0; j < 4; ++j)
        acc[i + 4][j] = __builtin_amdgcn_mfma_f32_16x16x32_bf16(ag[i], bfr[j], acc[i + 4][j], 0, 0, 0);
    __builtin_amdgcn_s_setprio(0);
    // ---- once-per-tile counted gate + end barrier (tail: 6 -> 4 -> 0)
    if (tau + 3 < NT) {
      asm volatile("s_waitcnt vmcnt(6)\n\ts_barrier" ::: "memory");
    } else if (tau + 2 < NT) {
      asm volatile("s_waitcnt vmcnt(4)\n\ts_barrier" ::: "memory");
    } else if (tau + 1 < NT) {
      asm volatile("s_waitcnt vmcnt(0)\n\ts_barrier" ::: "memory");
    }
    __builtin_amdgcn_sched_barrier(0);
  }

  void* Cbase = chunk ? Cout2 : Cout;
#pragma unroll
  for (int i = 0; i < 8; ++i) {
#pragma unroll
    for (int j = 0; j < 4; ++j) {
      int gn = bn256 + wn * 64 + j * 16 + l16;
      float bv = chunk ? 0.f : bias[gn];
      if (EPI == 3 && gn >= 2048) {
        int h = (gn >> 6) & 15, s = gn & 63;
        int gm0 = bm256 + wm * 128 + i * 16 + quad * 4;
        int b = gm0 >> 11, tt0 = gm0 & 2047;
        unsigned short* vt = (unsigned short*)Cout + 16777216L;
        ushort4 us;
        us.x = f2b(acc[i][j][0] + bv);
        us.y = f2b(acc[i][j][1] + bv);
        us.z = f2b(acc[i][j][2] + bv);
        us.w = f2b(acc[i][j][3] + bv);
        *(ushort4*)(vt + (((long)(b * 16 + h)) * 64 + s) * 2048 + tt0) = us;
      } else {
#pragma unroll
        for (int r = 0; r < 4; ++r) {
          int gm = bm256 + wm * 128 + i * 16 + quad * 4 + r;
          float v = acc[i][j][r] + bv;
          if (EPI == 2) v = fmaxf(v, 0.f);
          if (EPI == 0) {
            ((float*)Cbase)[(long)gm * N + gn] = v;
          } else if (EPI == 2) {
            ((unsigned short*)Cbase)[(long)gm * N + gn] = f2b(v);
          } else {  // EPI==3, q/k rows
            float sc = (gn < 1024) ? 0.18033688011112042f : 1.0f;  // 0.125*log2(e)
            ((unsigned short*)Cbase)[(long)gm * 2048 + gn] = f2b(v * sc);
          }
        }
      }
    }
  }
}

// ---------------- MFMA flash attention (reg-P, 64-row paired q-tiles) --------
// qk[m][2048] (q cols 0..1023 pre-scaled by 0.125*log2e, k cols 1024..2047),
// vt[b,h,s,t] at elem offset 16M. 1-D grid 1024, 256 thr = 4 waves.
// id = (g&7) + 8*qa + 128*(g>>3), g = h + 16*b: the 16 pair-blocks of one
// (b,h) share an XCD. Block: q-tiles qa and qb=31-qa (64 rows each); staged
// k-tiles 0..qb serve both -> 33 works, uniform. Wave w owns q rows
// [qt*64 + w*16, +16). P fully in-register via pi-permuted K rows.
__global__ __launch_bounds__(256) void attn_mfma(const unsigned short* __restrict__ qkv,
                                                 unsigned short* __restrict__ outp) {
  __shared__ __align__(16) unsigned short Ks[2][64 * 64];
  __shared__ __align__(16) unsigned short Vts[2][64 * 64];
  int id = blockIdx.x;
  int qa = (id >> 3) & 15, qb = 31 - qa;
  int g = (id & 7) | ((id >> 7) << 3);
  int h = g & 15, b = g >> 4;
  int t = threadIdx.x;
  int w = t >> 6, lane = t & 63, quad = lane >> 4, l16 = lane & 15;
  const unsigned short* qg = qkv + (long)(b * 2048) * 2048 + h * 64;
  const unsigned short* kg = qg + 1024;
  const unsigned short* vg = qkv + 16777216L + (((long)(b * 16 + h)) * 64) * 2048;

  // Q frags (B-operand for S^T): [ks]; row = qt*64 + w*16 + l16
  bf16x8 qfa[2], qfb[2];
#pragma unroll
  for (int ks = 0; ks < 2; ++ks) {
    qfa[ks] = *(const bf16x8*)(qg + (long)(qa * 64 + w * 16 + l16) * 2048 + ks * 32 + quad * 8);
    qfb[ks] = *(const bf16x8*)(qg + (long)(qb * 64 + w * 16 + l16) * 2048 + ks * 32 + quad * 8);
  }

  int sr = t >> 2, c4 = t & 3;
  int fsr = (sr & 3) | (((sr >> 3) & 1) << 2);          // store-side swizzle
  int ws0 = sr * 64 + (((2 * c4) ^ fsr) * 8);           // slot 2c
  int ws1 = sr * 64 + (((2 * c4 + 1) ^ fsr) * 8);       // slot 2c+1
  const unsigned short* kp = kg + (long)sr * 2048 + c4 * 16;
  const unsigned short* vp = vg + (long)sr * 2048 + c4 * 16;
  int4 kv0 = *(const int4*)kp, kv1 = *(const int4*)(kp + 8);
  int4 vv0 = *(const int4*)vp, vv1 = *(const int4*)(vp + 8);
  kp += (long)64 * 2048;
  vp += 64;

  f32x4 oa[4] = {}, ob[4] = {};
  f32x4 la = {}, lb = {};
  const short ONE = 0x3F80;
  bf16x8 ones = {ONE, ONE, ONE, ONE, ONE, ONE, ONE, ONE};

  int fs = l16 & 7;                                     // f(pi-row) for K reads
  int fv = (l16 & 3) | (((l16 >> 3) & 1) << 2);         // f(row) for V reads
  int qrow = w * 16 + l16;                              // q row within 64-tile

  // one k-tile (64 k) x 16 q rows, P fully in-register
  auto process = [&](const bf16x8 (&qf)[2], bool diag,
                     f32x4 (&oacc)[4], f32x4& lacc,
                     const unsigned short* Kb, const unsigned short* Vb) {
#pragma unroll
    for (int kc = 0; kc < 2; ++kc) {
      unsigned int apw[4];
#pragma unroll
      for (int aa = 0; aa < 2; ++aa) {
        int row = 8 * (l16 >> 2) + (l16 & 3) + 4 * aa + 32 * kc;  // pi(aa,kc,l16)
        const unsigned short* kr = Kb + row * 64;
        bf16x8 kf0 = *(const bf16x8*)(kr + (quad ^ fs) * 8);
        bf16x8 kf1 = *(const bf16x8*)(kr + ((quad ^ 4 ^ fs)) * 8);
        f32x4 st = {};
        st = __builtin_amdgcn_mfma_f32_16x16x32_bf16(kf0, qf[0], st, 0, 0, 0);
        st = __builtin_amdgcn_mfma_f32_16x16x32_bf16(kf1, qf[1], st, 0, 0, 0);
        if (diag) {
          int kq = 8 * quad + 4 * aa + 32 * kc;
#pragma unroll
          for (int r = 0; r < 4; ++r)
            if (kq + r > qrow) st[r] = -1e30f;
        }
        apw[aa * 2]     = pk2b(exp2f(st[0]), exp2f(st[1]));
        apw[aa * 2 + 1] = pk2b(exp2f(st[2]), exp2f(st[3]));
      }
      union { unsigned int u[4]; bf16x8 v; } ap;
#pragma unroll
      for (int u = 0; u < 4; ++u) ap.u[u] = apw[u];
      lacc = __builtin_amdgcn_mfma_f32_16x16x32_bf16(ap.v, ones, lacc, 0, 0, 0);
#pragma unroll
      for (int sg = 0; sg < 4; ++sg) {
        int vrow = sg * 16 + l16;
        bf16x8 vf = *(const bf16x8*)(Vb + vrow * 64 + (((4 * kc + quad) ^ fv) * 8));
        oacc[sg] = __builtin_amdgcn_mfma_f32_16x16x32_bf16(ap.v, vf, oacc[sg], 0, 0, 0);
      }
    }
  };

  int nkt = qb + 1;
  for (int kt = 0; kt < nkt; ++kt) {
    unsigned short* Kb = &Ks[kt & 1][0];
    unsigned short* Vb = &Vts[kt & 1][0];
    *(int4*)(Kb + ws0) = kv0;
    *(int4*)(Kb + ws1) = kv1;
    *(int4*)(Vb + ws0) = vv0;
    *(int4*)(Vb + ws1) = vv1;
    __syncthreads();
    if (kt + 1 < nkt) {  // prefetch next tile behind compute
      kv0 = *(const int4*)kp; kv1 = *(const int4*)(kp + 8);
      vv0 = *(const int4*)vp; vv1 = *(const int4*)(vp + 8);
      kp += (long)64 * 2048;
      vp += 64;
    }
    process(qfb, kt == qb, ob, lb, Kb, Vb);                 // heavy tile
    if (kt <= qa) process(qfa, kt == qa, oa, la, Kb, Vb);   // light tile
  }

  auto epi = [&](int qt, f32x4 (&oacc)[4], f32x4& lacc) {
#pragma unroll
    for (int r = 0; r < 4; ++r) {
      float invl = 1.f / lacc[r];
      int row = qt * 64 + w * 16 + quad * 4 + r;
      unsigned short* op = outp + ((long)(b * 2048 + row)) * 1024 + h * 64;
#pragma unroll
      for (int sg = 0; sg < 4; ++sg) op[sg * 16 + l16] = f2b(oacc[sg][r] * invl);
    }
  };
  epi(qa, oa, la);
  epi(qb, ob, lb);
}

// ---------------- residual + LayerNorm (optional 3rd addend: split-K partial) --
__global__ __launch_bounds__(256) void ln_kernel(const float* __restrict__ a,
                                                 const float* __restrict__ a2,
                                                 const float* __restrict__ res,
                                                 const float* __restrict__ gam,
                                                 const float* __restrict__ bet,
                                                 float* __restrict__ outf,
                                                 unsigned short* __restrict__ outb) {
  int row = blockIdx.x, t = threadIdx.x;
  float4 av = *(const float4*)(a + (long)row * 1024 + t * 4);
  float4 rv = *(const float4*)(res + (long)row * 1024 + t * 4);
  float v0 = av.x + rv.x, v1 = av.y + rv.y, v2 = av.z + rv.z, v3 = av.w + rv.w;
  if (a2) {
    float4 a2v = *(const float4*)(a2 + (long)row * 1024 + t * 4);
    v0 += a2v.x; v1 += a2v.y; v2 += a2v.z; v3 += a2v.w;
  }
  float s = v0 + v1 + v2 + v3;
  float ss = v0 * v0 + v1 * v1 + v2 * v2 + v3 * v3;
#pragma unroll
  for (int off = 32; off >= 1; off >>= 1) {
    s += __shfl_down(s, off);
    ss += __shfl_down(ss, off);
  }
  __shared__ float sb[4], ssb[4];
  __shared__ float mean_s, inv_s;
  int w = t >> 6, lane = t & 63;
  if (lane == 0) { sb[w] = s; ssb[w] = ss; }
  __syncthreads();
  if (t == 0) {
    float S = sb[0] + sb[1] + sb[2] + sb[3];
    float SS = ssb[0] + ssb[1] + ssb[2] + ssb[3];
    float mean = S * (1.f / 1024.f);
    float var = SS * (1.f / 1024.f) - mean * mean;
    mean_s = mean;
    inv_s = rsqrtf(var + 1e-5f);
  }
  __syncthreads();
  float mean = mean_s, inv = inv_s;
  int c = t * 4;
  float4 gv = *(const float4*)(gam + c);
  float4 bv = *(const float4*)(bet + c);
  float y0 = (v0 - mean) * inv * gv.x + bv.x;
  float y1 = (v1 - mean) * inv * gv.y + bv.y;
  float y2 = (v2 - mean) * inv * gv.z + bv.z;
  float y3 = (v3 - mean) * inv * gv.w + bv.w;
  *(float4*)(outf + (long)row * 1024 + c) = make_float4(y0, y1, y2, y3);
  if (outb) {
    *(ushort4*)(outb + (long)row * 1024 + c) = make_ushort4(f2b(y0), f2b(y1), f2b(y2), f2b(y3));
  }
}

extern "C" void kernel_launch(void* const* d_in, const int* in_sizes, int n_in,
                              void* d_out, int out_size, void* d_ws, size_t ws_size,
                              hipStream_t stream) {
  const float* x      = (const float*)d_in[0];
  const float* w_attn = (const float*)d_in[1];
  const float* b_attn = (const float*)d_in[2];
  const float* w_proj = (const float*)d_in[3];
  const float* b_proj = (const float*)d_in[4];
  const float* ln1_g  = (const float*)d_in[5];
  const float* ln1_b  = (const float*)d_in[6];
  const float* w_ff1  = (const float*)d_in[7];
  const float* b_ff1  = (const float*)d_in[8];
  const float* w_ff2  = (const float*)d_in[9];
  const float* b_ff2  = (const float*)d_in[10];
  const float* ln2_g  = (const float*)d_in[11];
  const float* ln2_b  = (const float*)d_in[12];

  const long M = 8192, E = 1024;
  char* ws = (char*)d_ws;
  unsigned short* xb   = (unsigned short*)ws; ws += M * E * 2;           // 16 MiB
  unsigned short* wTa  = (unsigned short*)ws; ws += 3072L * 1024 * 2;    // 6
  unsigned short* wTp  = (unsigned short*)ws; ws += 1024L * 1024 * 2;    // 2
  unsigned short* wTf1 = (unsigned short*)ws; ws += 4096L * 1024 * 2;    // 8
  unsigned short* wTf2 = (unsigned short*)ws; ws += 4096L * 1024 * 2;    // 8
  unsigned short* qkvb = (unsigned short*)ws; ws += M * 3072 * 2;        // 48 (qk rows 32 MiB | vt 16 MiB)
  unsigned short* attb = (unsigned short*)ws; ws += M * E * 2;           // 16
  float* a1f = (float*)ws; ws += M * E * 4;                              // 32
  float* x1f = (float*)ws; ws += M * E * 4;                              // 32
  unsigned short* x1b = (unsigned short*)ws; ws += M * E * 2;            // 16  => 184 MiB
  unsigned short* hb = qkvb;   // overlays consumed qkv+attb space
  float* f2 = a1f;
  // split-K partial buffers (reuse dead workspace, both 32 MiB fp32):
  float* prj1 = (float*)qkvb;   // qk region dead after attn; ln1 consumes before ff1
  float* ff21 = (float*)d_ws;   // xb+wTa+wTp+(part of)wTf1 dead by ff2

  cvt_bf16<<<dim3((M * E) / 4 / 256), dim3(256), 0, stream>>>(x, xb, M * E);
  transpose_bf16<<<dim3(3072 / 32, 1024 / 32), dim3(32, 8), 0, stream>>>(w_attn, wTa, 1024, 3072);
  transpose_bf16<<<dim3(1024 / 32, 1024 / 32), dim3(32, 8), 0, stream>>>(w_proj, wTp, 1024, 1024);
  transpose_bf16<<<dim3(4096 / 32, 1024 / 32), dim3(32, 8), 0, stream>>>(w_ff1, wTf1, 1024, 4096);
  transpose_bf16<<<dim3(1024 / 32, 4096 / 32), dim3(32, 8), 0, stream>>>(w_ff2, wTf2, 4096, 1024);
  // qkv projection (384 blocks), attention-layout epilogue
  gemm256<3><<<dim3(384, 1), dim3(512), 0, stream>>>(xb, wTa, b_attn, qkvb, nullptr, 3072, 1024, 1024);
  // MFMA flash attention (reg-P, 64-row paired q-tiles)
  attn_mfma<<<dim3(1024), dim3(256), 0, stream>>>(qkvb, attb);
  // attn output projection: split-K=2 -> 256 blocks = 1 full round
  gemm256<0><<<dim3(128, 2), dim3(512), 0, stream>>>(attb, wTp, b_proj, a1f, prj1, 1024, 512, 1024);
  ln_kernel<<<dim3(8192), dim3(256), 0, stream>>>(a1f, prj1, x, ln1_g, ln1_b, x1f, x1b);
  // ff1 (512 blocks = 2 rounds)
  gemm256<2><<<dim3(512, 1), dim3(512), 0, stream>>>(x1b, wTf1, b_ff1, hb, nullptr, 4096, 1024, 1024);
  // ff2: split-K=2 -> 256 blocks = 1 full round, K chunks of 2048
  gemm256<0><<<dim3(128, 2), dim3(512), 0, stream>>>(hb, wTf2, b_ff2, f2, ff21, 1024, 2048, 4096);
  ln_kernel<<<dim3(8192), dim3(256), 0, stream>>>(f2, ff21, x1f, ln2_g, ln2_b, (float*)d_out, nullptr);
}